// Round 1
// baseline (72.108 us; speedup 1.0000x reference)
//
#include <hip/hip_runtime.h>

// SoftToHardEncoder: B=16, L=16, H=64, W=64, NUM_CODES=64
// Outputs (concat, fp32): soft_symbols[B,H,W,L], hard_symbols[B,H,W,L], idxes[B,H,W,L]
//
// Trick: exp(-|z-w|) == min(e^z * e^-w, e^-z * e^w)  -> 2 exps per element
// instead of 64; inner loop is 9 full-rate VALU ops per code.
// Argmin is tracked on the exact fp32 |z-w| so idx/hard bit-match the numpy ref.

namespace {
constexpr int kL = 16;
constexpr int kC = 64;
constexpr int kHW = 64 * 64;        // 4096
constexpr int kN = 16 * kHW * kL;   // 1,048,576 elements per output
constexpr int kStride = 68;         // LDS row stride in floats: 272B = 16B-aligned,
                                    // bank = (4l+c)%32 -> worst 2-way conflict (free)
constexpr float kLog2e = 1.44269504088896340736f;
}

__global__ __launch_bounds__(256) void soft_to_hard_kernel(
    const float* __restrict__ z,
    const float* __restrict__ codes,
    float* __restrict__ out)
{
    __shared__ float wl[kL * kStride];
    __shared__ float pl[kL * kStride];  // e^{+w}
    __shared__ float ql[kL * kStride];  // e^{-w}

    const int tid = threadIdx.x;

    // Stage codebook + exp tables into LDS: 1024 codes, 4 per thread.
    {
        const int base = tid << 2;          // 0..1020
        const int l = base >> 6;
        const int c = base & 63;
        const float4 wv = *reinterpret_cast<const float4*>(codes + base);
        const int o = l * kStride + c;
        wl[o + 0] = wv.x; wl[o + 1] = wv.y; wl[o + 2] = wv.z; wl[o + 3] = wv.w;
        pl[o + 0] = exp2f(wv.x * kLog2e);
        pl[o + 1] = exp2f(wv.y * kLog2e);
        pl[o + 2] = exp2f(wv.z * kLog2e);
        pl[o + 3] = exp2f(wv.w * kLog2e);
        ql[o + 0] = exp2f(-wv.x * kLog2e);
        ql[o + 1] = exp2f(-wv.y * kLog2e);
        ql[o + 2] = exp2f(-wv.z * kLog2e);
        ql[o + 3] = exp2f(-wv.w * kLog2e);
    }
    __syncthreads();

    // Output-layout mapping: gid = ((b*HW + hw) * L + l)  -> coalesced stores.
    const int gid = blockIdx.x * 256 + tid;
    const int l   = gid & (kL - 1);
    const int bhw = gid >> 4;
    const int b   = gid >> 16;           // bhw / 4096
    const int hw  = bhw & (kHW - 1);

    // z is [B, L, H, W]
    const float zv = z[(b << 16) + (l << 12) + hw];

    const float t    = zv * kLog2e;
    const float E    = exp2f(t);    // e^{z}
    const float Einv = exp2f(-t);   // e^{-z}

    const float* __restrict__ wr = wl + l * kStride;
    const float* __restrict__ pr = pl + l * kStride;
    const float* __restrict__ qr = ql + l * kStride;

    float mind = 3.4e38f;
    int   idx  = 0;
    float sum  = 0.0f;
    float wsum = 0.0f;

#define STEP(wc, pc, qc, cc)                                  \
    {                                                         \
        const float d = __builtin_fabsf(zv - (wc));           \
        idx  = (d < mind) ? (cc) : idx;                       \
        mind = fminf(d, mind);                                \
        const float e = fminf(E * (qc), Einv * (pc));         \
        sum += e;                                             \
        wsum = __builtin_fmaf(e, (wc), wsum);                 \
    }

#pragma unroll
    for (int c0 = 0; c0 < kC; c0 += 4) {
        const float4 wv = *reinterpret_cast<const float4*>(wr + c0);
        const float4 pv = *reinterpret_cast<const float4*>(pr + c0);
        const float4 qv = *reinterpret_cast<const float4*>(qr + c0);
        STEP(wv.x, pv.x, qv.x, c0 + 0);
        STEP(wv.y, pv.y, qv.y, c0 + 1);
        STEP(wv.z, pv.z, qv.z, c0 + 2);
        STEP(wv.w, pv.w, qv.w, c0 + 3);
    }
#undef STEP

    const float soft = wsum / sum;
    const float hard = wr[idx];

    out[gid]          = soft;
    out[kN + gid]     = hard;
    out[2 * kN + gid] = (float)idx;
}

extern "C" void kernel_launch(void* const* d_in, const int* in_sizes, int n_in,
                              void* d_out, int out_size, void* d_ws, size_t ws_size,
                              hipStream_t stream) {
    const float* z     = (const float*)d_in[0];  // [16,16,64,64] fp32
    const float* codes = (const float*)d_in[1];  // [16,64] fp32
    float* out = (float*)d_out;                  // 3 * 1,048,576 fp32

    const int threads = 256;
    const int blocks  = kN / threads;            // 4096
    soft_to_hard_kernel<<<blocks, threads, 0, stream>>>(z, codes, out);
}